// Round 4
// baseline (2862.216 us; speedup 1.0000x reference)
//
#include <hip/hip_runtime.h>
#include <hip/hip_bf16.h>

// STDP IF-neuron network, T=50 sequential steps.
// x_seq [50,256,1024] f32, weight [2048,1024] f32 -> spike_trace [256,2048] f32.
//
// Key insight: the recurrence is embarrassingly parallel across H.
// v[b,h], s[b,h], W[h,:] depend only on W[h,:] history + read-only x.
// => ONE persistent kernel: 128 blocks x 512 thr, each owns a 16-h slab.
//    W fp32 master + bf16 hi/lo splits live in LDS for all 50 steps.
//    v, trace live in registers. 2 barriers/step. Zero W global traffic.
// fwd GEMM: 3-product bf16 split compensation (hh + hl + lh), MFMA
//   A-fragments read directly from global (L2-resident x slices).
// wupd GEMM: s (exact {0,1} bf16, in LDS) x transposed splits xT (global).
// Accumulation orders identical to round 3 => bit-identical output.

#define T_STEPS 50
#define BATCH   256
#define DIM     1024
#define HID     2048
#define HT      16
#define LR_OVER_B (0.005f / 256.0f)

// LDS: wfs f32[16][1024] | wh u16[16][1024] swz | wl u16[16][1024] swz | s u16[16][256] swz
#define SMEM_BYTES (65536 + 32768 + 32768 + 8192)

typedef __attribute__((ext_vector_type(8))) short short8v;
typedef __attribute__((ext_vector_type(4))) float f32x4;

static __device__ __forceinline__ ushort f32_to_bf16u(float f) {
    __hip_bfloat16 h = __float2bfloat16(f);
    return __builtin_bit_cast(unsigned short, h);
}
static __device__ __forceinline__ float bf16u_to_f32(ushort u) {
    __hip_bfloat16 h = __builtin_bit_cast(__hip_bfloat16, u);
    return __bfloat162float(h);
}

// ---------------- prep: row-major + transposed bf16 splits of x -----------
__global__ __launch_bounds__(256) void prep_x(
    const float* __restrict__ x,
    ushort* __restrict__ xh,  ushort* __restrict__ xl,    // [T,B,D]
    ushort* __restrict__ xTh, ushort* __restrict__ xTl)   // [T,D,B]
{
    __shared__ float tile[32][33];
    const int t  = blockIdx.z;
    const int d0 = blockIdx.x * 32;
    const int b0 = blockIdx.y * 32;
    const int tx = threadIdx.x & 31;
    const int ty = threadIdx.x >> 5;         // 0..7
    const float* xt = x + (size_t)t * BATCH * DIM;
    ushort* xht = xh + (size_t)t * BATCH * DIM;
    ushort* xlt = xl + (size_t)t * BATCH * DIM;
#pragma unroll
    for (int r = 0; r < 32; r += 8) {
        size_t gi = (size_t)(b0 + ty + r) * DIM + d0 + tx;
        float v = xt[gi];
        tile[ty + r][tx] = v;
        ushort hi = f32_to_bf16u(v);
        xht[gi] = hi;
        xlt[gi] = f32_to_bf16u(v - bf16u_to_f32(hi));
    }
    __syncthreads();
    ushort* oth = xTh + (size_t)t * DIM * BATCH;
    ushort* otl = xTl + (size_t)t * DIM * BATCH;
#pragma unroll
    for (int r = 0; r < 32; r += 8) {
        float v = tile[tx][ty + r];          // d = d0+ty+r, b = b0+tx
        ushort hi = f32_to_bf16u(v);
        size_t gi = (size_t)(d0 + ty + r) * BATCH + b0 + tx;
        oth[gi] = hi;
        otl[gi] = f32_to_bf16u(v - bf16u_to_f32(hi));
    }
}

// ---------------- THE persistent kernel -----------------------------------
__global__ __launch_bounds__(512, 1) void stdp_persistent(
    const ushort* __restrict__ xh,  const ushort* __restrict__ xl,   // [T,B,D]
    const ushort* __restrict__ xTh, const ushort* __restrict__ xTl,  // [T,D,B]
    const float* __restrict__ weight,                                 // [H,D]
    float* __restrict__ out)                                          // [B,H]
{
    extern __shared__ char smem[];
    float*  wfs = (float*)smem;                    // [16][1024] fp32 master
    ushort* wh  = (ushort*)(smem + 65536);         // [16][1024] swizzled
    ushort* wl  = (ushort*)(smem + 98304);         // [16][1024] swizzled
    ushort* sl  = (ushort*)(smem + 131072);        // [16][256]  swizzled

    const int tid  = threadIdx.x;
    const int lane = tid & 63;
    const int w    = tid >> 6;                     // wave 0..7
    const int h0   = blockIdx.x * HT;

    const int fr = lane & 15;                      // fragment row index
    const int kg = (lane >> 4) * 8;                // fragment k-group offset
    const int rq = (lane >> 4) * 4;                // D-fragment row base

    // ---- init: W slab -> LDS fp32 + swizzled bf16 splits ----
#pragma unroll
    for (int i = 0; i < 32; ++i) {
        int flat = i * 512 + tid;                  // 16384 = 16*1024
        int h = flat >> 10, d = flat & 1023;
        float wv = weight[(size_t)(h0 + h) * DIM + d];
        wfs[flat] = wv;
        ushort hi = f32_to_bf16u(wv);
        int sidx = (h << 10) | (d ^ ((h & 7) << 3));
        wh[sidx] = hi;
        wl[sidx] = f32_to_bf16u(wv - bf16u_to_f32(hi));
    }
    __syncthreads();

    const f32x4 z4 = {0.f, 0.f, 0.f, 0.f};
    f32x4 vmem[2] = {z4, z4};                      // membrane potential (regs)
    f32x4 trc[2]  = {z4, z4};                      // spike trace (regs)

    struct Frag4 { short8v a0h, a0l, a1h, a1l; };

    for (int t = 0; t < T_STEPS; ++t) {
        const ushort* xht = xh + (size_t)t * BATCH * DIM;
        const ushort* xlt = xl + (size_t)t * BATCH * DIM;

        // ================= fwd: mem = x @ W^T (3-product split) ===========
        f32x4 acc0 = z4, acc1 = z4;
        const size_t rbase0 = (size_t)(w * 32 + fr) * DIM + kg;
        const size_t rbase1 = rbase0 + (size_t)16 * DIM;

        auto LDA = [&](int k) {
            Frag4 f;
            f.a0h = *(const short8v*)&xht[rbase0 + k];
            f.a0l = *(const short8v*)&xlt[rbase0 + k];
            f.a1h = *(const short8v*)&xht[rbase1 + k];
            f.a1l = *(const short8v*)&xlt[rbase1 + k];
            return f;
        };

        Frag4 fc = LDA(0);
        Frag4 fm = LDA(32);
#pragma unroll 4
        for (int k = 0; k < DIM; k += 32) {
            int kn = (k + 64 < DIM) ? k + 64 : 0;      // clamp (dead on tail)
            Frag4 fn = LDA(kn);
            int bidx = (fr << 10) | ((k + kg) ^ ((fr & 7) << 3));
            short8v bh = *(const short8v*)&wh[bidx];
            short8v bl = *(const short8v*)&wl[bidx];
            acc0 = __builtin_amdgcn_mfma_f32_16x16x32_bf16(fc.a0h, bh, acc0, 0, 0, 0);
            acc0 = __builtin_amdgcn_mfma_f32_16x16x32_bf16(fc.a0h, bl, acc0, 0, 0, 0);
            acc0 = __builtin_amdgcn_mfma_f32_16x16x32_bf16(fc.a0l, bh, acc0, 0, 0, 0);
            acc1 = __builtin_amdgcn_mfma_f32_16x16x32_bf16(fc.a1h, bh, acc1, 0, 0, 0);
            acc1 = __builtin_amdgcn_mfma_f32_16x16x32_bf16(fc.a1h, bl, acc1, 0, 0, 0);
            acc1 = __builtin_amdgcn_mfma_f32_16x16x32_bf16(fc.a1l, bh, acc1, 0, 0, 0);
            fc = fm; fm = fn;
        }

        // ---- fused IF update + spike to LDS (D: row=b, col=h) ----
#pragma unroll
        for (int tile = 0; tile < 2; ++tile) {
            const f32x4 a = (tile == 0) ? acc0 : acc1;
#pragma unroll
            for (int j = 0; j < 4; ++j) {
                int b = w * 32 + tile * 16 + rq + j;
                float nv = vmem[tile][j] + a[j];
                float sp = (nv >= 1.0f) ? 1.0f : 0.0f;
                vmem[tile][j] = (nv >= 1.0f) ? 0.0f : nv;
                trc[tile][j] += sp;
                sl[(fr << 8) | (b ^ ((fr & 7) << 3))] = sp != 0.0f ? (ushort)0x3F80 : (ushort)0;
            }
        }

        __syncthreads();   // barrier 1: s complete, fwd whl reads done

        // ================= wupd: W += c * s^T @ x (2-product) =============
        if (t < T_STEPS - 1) {
            const ushort* xTht = xTh + (size_t)t * DIM * BATCH;
            const ushort* xTlt = xTl + (size_t)t * DIM * BATCH;

#pragma unroll
            for (int g = 0; g < 2; ++g) {          // 2 groups x 4 d-tiles
                f32x4 du[4] = {z4, z4, z4, z4};
                const int dbase = (w * 8 + g * 4) * 16 + fr;

                struct BFrag { short8v h[4], l[4]; };
                auto LDB = [&](int b0) {
                    BFrag f;
#pragma unroll
                    for (int q = 0; q < 4; ++q) {
                        size_t gi = (size_t)(dbase + q * 16) * BATCH + b0 + kg;
                        f.h[q] = *(const short8v*)&xTht[gi];
                        f.l[q] = *(const short8v*)&xTlt[gi];
                    }
                    return f;
                };

                BFrag cur = LDB(0);
#pragma unroll
                for (int b0 = 0; b0 < BATCH; b0 += 32) {
                    int nb = (b0 + 32 < BATCH) ? b0 + 32 : 0;
                    BFrag nxt = LDB(nb);
                    short8v ah = *(const short8v*)&sl[(fr << 8) | ((b0 + kg) ^ ((fr & 7) << 3))];
#pragma unroll
                    for (int q = 0; q < 4; ++q) {
                        du[q] = __builtin_amdgcn_mfma_f32_16x16x32_bf16(ah, cur.h[q], du[q], 0, 0, 0);
                        du[q] = __builtin_amdgcn_mfma_f32_16x16x32_bf16(ah, cur.l[q], du[q], 0, 0, 0);
                    }
                    cur = nxt;
                }

                // ---- W update + re-split (D: row=h, col=d); own d-range ----
#pragma unroll
                for (int q = 0; q < 4; ++q) {
                    const int d = dbase + q * 16;
#pragma unroll
                    for (int j = 0; j < 4; ++j) {
                        const int h = rq + j;
                        const int widx = (h << 10) | d;
                        float wv = fmaf(LR_OVER_B, du[q][j], wfs[widx]);
                        wfs[widx] = wv;
                        ushort hi = f32_to_bf16u(wv);
                        const int sidx = (h << 10) | (d ^ ((h & 7) << 3));
                        wh[sidx] = hi;
                        wl[sidx] = f32_to_bf16u(wv - bf16u_to_f32(hi));
                    }
                }
            }
        }

        __syncthreads();   // barrier 2: whl consistent for next fwd
    }

    // ---- write trace (registers) to d_out [B,H] ----
#pragma unroll
    for (int tile = 0; tile < 2; ++tile) {
#pragma unroll
        for (int j = 0; j < 4; ++j) {
            int b = w * 32 + tile * 16 + rq + j;
            out[(size_t)b * HID + h0 + fr] = trc[tile][j];
        }
    }
}

// ---------------- fallback fp32 kernels (round-0, small ws) ---------------
#define BK 16
__global__ __launch_bounds__(256) void stdp_fwd_if(
    const float* __restrict__ x, const float* __restrict__ w,
    float* __restrict__ v, float* __restrict__ s, float* __restrict__ trace)
{
    __shared__ float as[BK][64];
    __shared__ float bs[BK][64];
    const int tid = threadIdx.x;
    const int tx = tid & 15, ty = tid >> 4;
    const int b0 = blockIdx.y * 64, h0 = blockIdx.x * 64;
    const int row = tid >> 2, kq = (tid & 3) * 4;
    float acc[4][4] = {};
    for (int k0 = 0; k0 < DIM; k0 += BK) {
        float4 ga = *(const float4*)&x[(size_t)(b0 + row) * DIM + k0 + kq];
        float4 gb = *(const float4*)&w[(size_t)(h0 + row) * DIM + k0 + kq];
        __syncthreads();
        as[kq + 0][row] = ga.x; as[kq + 1][row] = ga.y;
        as[kq + 2][row] = ga.z; as[kq + 3][row] = ga.w;
        bs[kq + 0][row] = gb.x; bs[kq + 1][row] = gb.y;
        bs[kq + 2][row] = gb.z; bs[kq + 3][row] = gb.w;
        __syncthreads();
#pragma unroll
        for (int kk = 0; kk < BK; ++kk) {
            float4 af = *(const float4*)&as[kk][ty * 4];
            float4 bf = *(const float4*)&bs[kk][tx * 4];
            float av[4] = {af.x, af.y, af.z, af.w};
            float bv[4] = {bf.x, bf.y, bf.z, bf.w};
#pragma unroll
            for (int m = 0; m < 4; ++m)
#pragma unroll
                for (int n = 0; n < 4; ++n)
                    acc[m][n] = fmaf(av[m], bv[n], acc[m][n]);
        }
    }
#pragma unroll
    for (int m = 0; m < 4; ++m) {
        size_t idx = (size_t)(b0 + ty * 4 + m) * HID + h0 + tx * 4;
        float4 vv = *(float4*)&v[idx];
        float4 tr = *(float4*)&trace[idx];
        float4 sv;
        float* vvp = &vv.x; float* trp = &tr.x; float* svp = &sv.x;
#pragma unroll
        for (int n = 0; n < 4; ++n) {
            float nv = vvp[n] + acc[m][n];
            float sp = (nv >= 1.0f) ? 1.0f : 0.0f;
            vvp[n] = (nv >= 1.0f) ? 0.0f : nv;
            svp[n] = sp; trp[n] += sp;
        }
        *(float4*)&v[idx] = vv;
        *(float4*)&s[idx] = sv;
        *(float4*)&trace[idx] = tr;
    }
}

__global__ __launch_bounds__(256) void stdp_wupd(
    const float* __restrict__ x, const float* __restrict__ s,
    float* __restrict__ w)
{
    __shared__ float ss[BK][64];
    __shared__ float xs[BK][64];
    const int tid = threadIdx.x;
    const int tx = tid & 15, ty = tid >> 4;
    const int h0 = blockIdx.y * 64, d0 = blockIdx.x * 64;
    const int krow = tid >> 4, c4 = (tid & 15) * 4;
    float acc[4][4] = {};
    for (int bk0 = 0; bk0 < BATCH; bk0 += BK) {
        float4 gs = *(const float4*)&s[(size_t)(bk0 + krow) * HID + h0 + c4];
        float4 gx = *(const float4*)&x[(size_t)(bk0 + krow) * DIM + d0 + c4];
        __syncthreads();
        *(float4*)&ss[krow][c4] = gs;
        *(float4*)&xs[krow][c4] = gx;
        __syncthreads();
#pragma unroll
        for (int kk = 0; kk < BK; ++kk) {
            float4 af = *(const float4*)&ss[kk][ty * 4];
            float4 bf = *(const float4*)&xs[kk][tx * 4];
            float av[4] = {af.x, af.y, af.z, af.w};
            float bv[4] = {bf.x, bf.y, bf.z, bf.w};
#pragma unroll
            for (int m = 0; m < 4; ++m)
#pragma unroll
                for (int n = 0; n < 4; ++n)
                    acc[m][n] = fmaf(av[m], bv[n], acc[m][n]);
        }
    }
#pragma unroll
    for (int m = 0; m < 4; ++m) {
        size_t idx = (size_t)(h0 + ty * 4 + m) * DIM + d0 + tx * 4;
        float4 wv = *(float4*)&w[idx];
        wv.x = fmaf(LR_OVER_B, acc[m][0], wv.x);
        wv.y = fmaf(LR_OVER_B, acc[m][1], wv.y);
        wv.z = fmaf(LR_OVER_B, acc[m][2], wv.z);
        wv.w = fmaf(LR_OVER_B, acc[m][3], wv.w);
        *(float4*)&w[idx] = wv;
    }
}

extern "C" void kernel_launch(void* const* d_in, const int* in_sizes, int n_in,
                              void* d_out, int out_size, void* d_ws, size_t ws_size,
                              hipStream_t stream) {
    (void)in_sizes; (void)n_in;
    const float* x_seq  = (const float*)d_in[0];   // [T, B, D]
    const float* weight = (const float*)d_in[1];   // [H, D]
    float* out = (float*)d_out;                    // [B, H]

    const size_t WN = (size_t)HID * DIM;
    const size_t BH = (size_t)BATCH * HID;
    const size_t XN = (size_t)T_STEPS * BATCH * DIM;  // 13107200

    const size_t need = 4 * XN * 2;                // xh | xl | xTh | xTl

    if (ws_size >= need) {
        ushort* xh  = (ushort*)d_ws;
        ushort* xl  = xh + XN;
        ushort* xTh = xl + XN;
        ushort* xTl = xTh + XN;

        prep_x<<<dim3(DIM / 32, BATCH / 32, T_STEPS), 256, 0, stream>>>(
            x_seq, xh, xl, xTh, xTl);

        hipFuncSetAttribute(reinterpret_cast<const void*>(&stdp_persistent),
                            hipFuncAttributeMaxDynamicSharedMemorySize,
                            SMEM_BYTES);
        stdp_persistent<<<HID / HT, 512, SMEM_BYTES, stream>>>(
            xh, xl, xTh, xTl, weight, out);
    } else {
        // fallback: fp32 VALU path (needs ~12.6 MB)
        float* w = (float*)d_ws;
        float* v = w + WN;
        float* s = v + BH;
        hipMemcpyAsync(w, weight, WN * 4, hipMemcpyDeviceToDevice, stream);
        hipMemsetAsync(v, 0, BH * 4, stream);
        hipMemsetAsync(out, 0, (size_t)out_size * 4, stream);
        dim3 blkA(256), grdA(HID / 64, BATCH / 64);
        dim3 blkB(256), grdB(DIM / 64, HID / 64);
        for (int t = 0; t < T_STEPS; ++t) {
            const float* xt = x_seq + (size_t)t * BATCH * DIM;
            stdp_fwd_if<<<grdA, blkA, 0, stream>>>(xt, w, v, s, out);
            if (t < T_STEPS - 1) {
                stdp_wupd<<<grdB, blkB, 0, stream>>>(xt, s, w);
            }
        }
    }
}